// Round 9
// baseline (271.566 us; speedup 1.0000x reference)
//
#include <hip/hip_runtime.h>

// BmmEnsemble: species-routed 4x8 MLP ensemble (384->160->128->96->1, CELU 0.1),
// mean over 8 models, global sum -> scalar.
// R14: PERSISTENT WORKERS + DYNAMIC QUEUE. All structural knobs (regs R6,
// prefetch R7, barriers R8/R13, pins R9, LDS-occupancy R10, slot width R13)
// are measured-neutral-or-worse; only work reductions helped. The unread
// counter: Occupancy 18.3% = (25+12.5)/2 -- with 784 = 3.06x256 blocks and
// 2 resident/CU, HALF the wall time runs 1 block/CU (272 stragglers), and
// since per-slot cost is latency-dominated (every throughput knob neutral),
// solo blocks run at the same per-block wall -> wall ~ 2*Tb for 1.53*Tb of
// work: ~25% lost to imbalance. Fix: grid=512 (2/CU resident full-time),
// work = 3136 (s,sb,m) model-units grabbed via global atomicAdd; per-unit
// body = R9/R12's proven 23-chunk 2-buffer __syncthreads pipeline. Per-unit
// energy flush (sb-dependent mask). a1 reloaded per unit from L3-hot aevb
// (group-check skips when consecutive units share (s,sb)); biases read from
// global (R10-proven); hpar dropped -> LDS 59.4KB.

#define NSP 4
#define NMODELS 8
#define NATOMS 50000
#define NPER (NATOMS / NSP)          // 12500
#define NPAD 12544                   // 98*128 padded rows per species
#define D0 384
#define D1 160
#define D2 128
#define D3 96
#define NRBLK ((NATOMS + 255) / 256) // 196
#define ABLK 128
#define BPS ((NPER + ABLK - 1) / ABLK) // 98 atom-blocks per species
#define FRAGS_SM 184                  // 120 (W1) + 40 (W2) + 24 (W3) fragments
#define NGROUP (NSP * BPS)            // 392 (s,sb) groups
#define NUNIT (NGROUP * NMODELS)      // 3136 model-units
#define NWORK 512                     // persistent worker blocks (2/CU)

typedef float f32x4 __attribute__((ext_vector_type(4)));
typedef __bf16 bf16x8 __attribute__((ext_vector_type(8)));

#define MFMA16(a, b, c) __builtin_amdgcn_mfma_f32_16x16x32_bf16((a), (b), (c), 0, 0, 0)

// ---- workspace layout (bytes) ----
#define PALL_BYTES ((size_t)NSP * NMODELS * FRAGS_SM * 1024)
#define PBIAS_OFF PALL_BYTES
#define PBIAS_BYTES ((size_t)NSP * NMODELS * 512 * 2)   // 1KB per (s,m)
#define ORDER_OFF (PBIAS_OFF + PBIAS_BYTES)
#define BCNT_OFF (ORDER_OFF + (size_t)NATOMS * 4)
#define BPFX_OFF (BCNT_OFF + (size_t)NRBLK * NSP * 4)
#define BASE_OFF (BPFX_OFF + (size_t)NRBLK * NSP * 4)
#define AEVB_OFF (BASE_OFF + 1024)                      // 64B-aligned
#define AEVB_BYTES ((size_t)NSP * NPAD * D0 * 2)        // 38.5 MB bf16
#define CTR_OFF (AEVB_OFF + AEVB_BYTES)                 // 4B work counter

static __device__ __forceinline__ unsigned short bfbits(float f) {
  __bf16 h = (__bf16)f;
  return __builtin_bit_cast(unsigned short, h);
}

static __device__ __forceinline__ float celu01(float x) {
  // celu(x, alpha=0.1) = max(x,0) + min(0, 0.1*(exp(x/0.1)-1))
  return fmaxf(x, 0.f) + 0.1f * fminf(0.f, __expf(x * 10.f) - 1.f);
}

// async global->LDS, 16 B per lane; LDS dest = wave-uniform base + lane*16
static __device__ __forceinline__ void gload16(const void* g, void* l) {
  __builtin_amdgcn_global_load_lds(
      (const __attribute__((address_space(1))) unsigned int*)g,
      (__attribute__((address_space(3))) unsigned int*)l, 16, 0, 0);
}

// ---------------- routing ----------------
__global__ __launch_bounds__(256) void count_kernel(const int* __restrict__ species,
                                                    int* __restrict__ bcnt) {
  __shared__ int cnt[NSP];
  int t = threadIdx.x;
  if (t < NSP) cnt[t] = 0;
  __syncthreads();
  int i = blockIdx.x * 256 + t;
  if (i < NATOMS) atomicAdd(&cnt[species[i]], 1);
  __syncthreads();
  if (t < NSP) bcnt[blockIdx.x * NSP + t] = cnt[t];
}

__global__ __launch_bounds__(256) void scan_kernel(const int* __restrict__ bcnt,
                                                   int* __restrict__ bpfx,
                                                   int* __restrict__ base) {
  int w = threadIdx.x >> 6;
  int lane = threadIdx.x & 63;
  __shared__ int totals[NSP];
  int carry = 0;
  for (int c = 0; c < (NRBLK + 63) / 64; ++c) {
    int idx = c * 64 + lane;
    int v = (idx < NRBLK) ? bcnt[idx * NSP + w] : 0;
    int incl = v;
    for (int off = 1; off < 64; off <<= 1) {
      int tv = __shfl_up(incl, off);
      if (lane >= off) incl += tv;
    }
    if (idx < NRBLK) bpfx[idx * NSP + w] = carry + incl - v;
    carry += __shfl(incl, 63);
  }
  if (lane == 0) totals[w] = carry;
  __syncthreads();
  if (threadIdx.x == 0) {
    int run = 0;
    for (int s = 0; s < NSP; ++s) { base[s] = run; run += totals[s]; }
  }
}

__global__ __launch_bounds__(256) void route_kernel(const int* __restrict__ species,
                                                    const int* __restrict__ bpfx,
                                                    const int* __restrict__ base,
                                                    int* __restrict__ order) {
  __shared__ int sp[256];
  int t = threadIdx.x;
  int i = blockIdx.x * 256 + t;
  sp[t] = (i < NATOMS) ? species[i] : -1;
  __syncthreads();
  if (i < NATOMS) {
    int s = sp[t];
    int rank = 0;
    for (int j = 0; j < t; ++j) rank += (sp[j] == s) ? 1 : 0;
    order[base[s] + bpfx[blockIdx.x * NSP + s] + rank] = i;
  }
}

// ---------------- routed bf16 aev pre-pack ----------------
// aevb[s*NPAD + slot][k] = bf16(aev[order[s*NPER+slot]][k]); pad rows zeroed.
__global__ __launch_bounds__(256) void aev_pack(const float* __restrict__ aev,
                                                const int* __restrict__ order,
                                                unsigned short* __restrict__ aevb) {
  int tid = blockIdx.x * 256 + threadIdx.x;   // NSP*NPAD*48 total
  const int perRow = D0 / 8;                  // 48
  int row = tid / perRow;
  int seg = tid - row * perRow;
  if (row >= NSP * NPAD) return;
  int s = row / NPAD;
  int slot = row - s * NPAD;
  unsigned short o[8];
  if (slot < NPER) {
    int src = order[s * NPER + slot];
    const float4* q = (const float4*)(aev + (size_t)src * D0 + seg * 8);
    float4 v0 = q[0], v1 = q[1];
    o[0] = bfbits(v0.x); o[1] = bfbits(v0.y); o[2] = bfbits(v0.z); o[3] = bfbits(v0.w);
    o[4] = bfbits(v1.x); o[5] = bfbits(v1.y); o[6] = bfbits(v1.z); o[7] = bfbits(v1.w);
  } else {
#pragma unroll
    for (int e = 0; e < 8; ++e) o[e] = 0;
  }
  *(int4*)(aevb + (size_t)row * D0 + seg * 8) = *(const int4*)o;
}

// ---------------- weight pre-pack into contiguous B-fragment stream ----------------
// pAll: per (s,m) block of FRAGS_SM fragments (1 KB each). Frag order within a
// layer: f = kf*NT + nt. Lane l, bf16 elem e: k = kf*32 + 8*(l>>4) + e ; n = nt*16 + (l&15).
__global__ __launch_bounds__(256) void pack_kernel(const float* __restrict__ W,
                                                   unsigned* __restrict__ dst,
                                                   int K, int N, int NT, int fragBase,
                                                   int total) {
  int tid = blockIdx.x * 256 + threadIdx.x;
  if (tid >= total) return;
  int per_sm = K * N / 2;            // dwords per (s,m)
  int smi = tid / per_sm;
  int rem = tid - smi * per_sm;
  int frag = rem >> 8;               // 256 dwords per fragment
  int wi = rem & 255;
  int l = wi >> 2, d = wi & 3;
  int kf = frag / NT;
  int nt = frag - kf * NT;
  int k = kf * 32 + ((l >> 4) << 3) + 2 * d;
  int n = nt * 16 + (l & 15);
  const float* p = W + ((size_t)smi * K + k) * N + n;
  unsigned lo = bfbits(p[0]);
  unsigned hi = bfbits(p[N]);
  dst[((size_t)smi * FRAGS_SM + fragBase + frag) * 256 + wi] = lo | (hi << 16);
}

// param pack: per (s,m) record of 512 shorts:
// [0:160) b1 bf16 | [160:288) b2 bf16 | [288:384) b3 bf16 | [384:480) W4 bf16 |
// [480:482) b4 as f32 bit halves | rest 0
__global__ __launch_bounds__(256) void param_pack(const float* __restrict__ b1,
                                                  const float* __restrict__ b2,
                                                  const float* __restrict__ b3,
                                                  const float* __restrict__ W4,
                                                  const float* __restrict__ b4,
                                                  unsigned short* __restrict__ dst) {
  int i = blockIdx.x * 256 + threadIdx.x;
  if (i >= NSP * NMODELS * 512) return;
  int smi = i >> 9, o = i & 511;
  unsigned short v = 0;
  if (o < 160) v = bfbits(b1[smi * 160 + o]);
  else if (o < 288) v = bfbits(b2[smi * 128 + (o - 160)]);
  else if (o < 384) v = bfbits(b3[smi * 96 + (o - 288)]);
  else if (o < 480) v = bfbits(W4[smi * 96 + (o - 384)]);
  else if (o < 482) {
    unsigned u = __builtin_bit_cast(unsigned, b4[smi]);
    v = (unsigned short)((o == 480) ? (u & 0xffffu) : (u >> 16));
  }
  dst[i] = v;
}

// ---------------- fused MLP: persistent workers, model-grain dynamic queue ----------------
__global__ __launch_bounds__(256, 2) void mlp_kernel(
    const unsigned short* __restrict__ aevb,
    const unsigned short* __restrict__ pAll, const unsigned short* __restrict__ pPar,
    int* __restrict__ uctr, float* __restrict__ out) {
  __shared__ alignas(16) unsigned short stage[2][4096]; // 16384 B, 2 chunk buffers
  __shared__ alignas(16) __bf16 hbuf[4][32][168];       // 43008 B, wave-private rows
  __shared__ int ush;
  // total LDS = 59392+ B -> 2 blocks/CU

  const int tid = threadIdx.x;
  const int w = tid >> 6;
  const int l = tid & 63;
  const int l15 = l & 15;
  const int l4 = l >> 4;

  bf16x8 a1[2][12];
  int cur_g = -1;

  while (true) {
    // ---- grab one (group, model) unit; block-uniform ----
    if (tid == 0) ush = atomicAdd(uctr, 1);
    __syncthreads();
    const int u = ush;
    if (u >= NUNIT) break;
    const int g = u >> 3;          // group = s*BPS + sb
    const int m = u & 7;           // model 0..7
    const int s = g / BPS;
    const int sb = g - s * BPS;

    // ---- A1 fragments for this (s, sb): reload only on group change ----
    if (g != cur_g) {
      cur_g = g;
#pragma unroll
      for (int mt = 0; mt < 2; ++mt) {
        int row = s * NPAD + sb * ABLK + w * 32 + mt * 16 + l15; // pad rows zero
        const bf16x8* rp = (const bf16x8*)(aevb + (size_t)row * D0 + l4 * 8);
#pragma unroll
        for (int kf = 0; kf < 12; ++kf) a1[mt][kf] = rp[kf * 4];
      }
    }

    // per-unit weight stream (184 frags) and param record
    const int smi = s * NMODELS + m;
    const char* wu = (const char*)pAll + (size_t)smi * FRAGS_SM * 1024 +
                     (size_t)w * 2048 + (size_t)l * 16;
    const unsigned short* pb = pPar + (size_t)smi * 512;

    // stage chunk c into buffer (c&1); 2KB per wave per chunk
    auto stg = [&](int c) {
      char* d = (char*)stage + (c & 1) * 8192 + w * 2048;
      const char* sp = wu + (size_t)c * 8192;
      gload16(sp, d);
      gload16(sp + 1024, d + 1024);
    };

    stg(0);
    __syncthreads(); // chunk 0 landed (sync waits vmem); also fences grab bcast

    f32x4 C[2][10];

    // ===== Layer 1: chunks 0..14 =====
#pragma unroll
    for (int mt = 0; mt < 2; ++mt)
#pragma unroll
      for (int nt = 0; nt < 10; ++nt) {
        f32x4 z; z[0] = z[1] = z[2] = z[3] = 0.f; C[mt][nt] = z;
      }
#pragma unroll
    for (int c = 0; c < 15; ++c) {
      stg(c + 1);
      const bf16x8* sbuf = (const bf16x8*)((const char*)stage + (c & 1) * 8192);
#pragma unroll
      for (int j = 0; j < 8; ++j) {
        const int f = c * 8 + j;    // kf = f/10, nt = f%10 (compile-time)
        bf16x8 b = sbuf[j * 64 + l];
        C[0][f % 10] = MFMA16(a1[0][f / 10], b, C[0][f % 10]);
        C[1][f % 10] = MFMA16(a1[1][f / 10], b, C[1][f % 10]);
      }
      __syncthreads();
    }
    // bias + celu -> hbuf (wave-private); biases from global (L2-hot)
#pragma unroll
    for (int nt = 0; nt < 10; ++nt) {
      float bias = (float)__builtin_bit_cast(__bf16, pb[nt * 16 + l15]);
#pragma unroll
      for (int mt = 0; mt < 2; ++mt)
#pragma unroll
        for (int r = 0; r < 4; ++r)
          hbuf[w][mt * 16 + l4 * 4 + r][nt * 16 + l15] = (__bf16)celu01(C[mt][nt][r] + bias);
    }

    // ===== Layer 2: chunks 15..19 (kf = lc, nt = j) =====
    bf16x8 a2[2][5];
#pragma unroll
    for (int mt = 0; mt < 2; ++mt)
#pragma unroll
      for (int kf = 0; kf < 5; ++kf)
        a2[mt][kf] = *(const bf16x8*)&hbuf[w][mt * 16 + l15][kf * 32 + l4 * 8];

#pragma unroll
    for (int mt = 0; mt < 2; ++mt)
#pragma unroll
      for (int nt = 0; nt < 8; ++nt) {
        f32x4 z; z[0] = z[1] = z[2] = z[3] = 0.f; C[mt][nt] = z;
      }
#pragma unroll
    for (int lc = 0; lc < 5; ++lc) {
      const int c = 15 + lc;
      stg(c + 1);
      const bf16x8* sbuf = (const bf16x8*)((const char*)stage + (c & 1) * 8192);
#pragma unroll
      for (int j = 0; j < 8; ++j) {
        bf16x8 b = sbuf[j * 64 + l];
        C[0][j] = MFMA16(a2[0][lc], b, C[0][j]);
        C[1][j] = MFMA16(a2[1][lc], b, C[1][j]);
      }
      __syncthreads();
    }
#pragma unroll
    for (int nt = 0; nt < 8; ++nt) {
      float bias = (float)__builtin_bit_cast(__bf16, pb[160 + nt * 16 + l15]);
#pragma unroll
      for (int mt = 0; mt < 2; ++mt)
#pragma unroll
        for (int r = 0; r < 4; ++r)
          hbuf[w][mt * 16 + l4 * 4 + r][nt * 16 + l15] = (__bf16)celu01(C[mt][nt][r] + bias);
    }

    // ===== Layer 3: chunks 20..22 (kf = f/6, nt = f%6) =====
    bf16x8 a3[2][4];
#pragma unroll
    for (int mt = 0; mt < 2; ++mt)
#pragma unroll
      for (int kf = 0; kf < 4; ++kf)
        a3[mt][kf] = *(const bf16x8*)&hbuf[w][mt * 16 + l15][kf * 32 + l4 * 8];

#pragma unroll
    for (int mt = 0; mt < 2; ++mt)
#pragma unroll
      for (int nt = 0; nt < 6; ++nt) {
        f32x4 z; z[0] = z[1] = z[2] = z[3] = 0.f; C[mt][nt] = z;
      }
#pragma unroll
    for (int lc = 0; lc < 3; ++lc) {
      const int c = 20 + lc;
      if (c + 1 < 23) stg(c + 1);
      const bf16x8* sbuf = (const bf16x8*)((const char*)stage + (c & 1) * 8192);
#pragma unroll
      for (int j = 0; j < 8; ++j) {
        const int f = lc * 8 + j;
        bf16x8 b = sbuf[j * 64 + l];
        C[0][f % 6] = MFMA16(a3[0][f / 6], b, C[0][f % 6]);
        C[1][f % 6] = MFMA16(a3[1][f / 6], b, C[1][f % 6]);
      }
      __syncthreads();
    }

    // ===== Layer 4 fold + per-unit flush (mask depends on sb) =====
    float e[2][4] = {{0.f, 0.f, 0.f, 0.f}, {0.f, 0.f, 0.f, 0.f}};
#pragma unroll
    for (int nt = 0; nt < 6; ++nt) {
      float b3v = (float)__builtin_bit_cast(__bf16, pb[288 + nt * 16 + l15]);
      float w4v = (float)__builtin_bit_cast(__bf16, pb[384 + nt * 16 + l15]);
#pragma unroll
      for (int mt = 0; mt < 2; ++mt)
#pragma unroll
        for (int r = 0; r < 4; ++r)
          e[mt][r] += celu01(C[mt][nt][r] + b3v) * w4v;
    }
    float b4v = ((const float*)pPar)[(size_t)smi * 256 + 240];
    float tot = 0.f;
#pragma unroll
    for (int mt = 0; mt < 2; ++mt)
#pragma unroll
      for (int r = 0; r < 4; ++r) {
        float v = e[mt][r];
        v += __shfl_xor(v, 1);
        v += __shfl_xor(v, 2);
        v += __shfl_xor(v, 4);
        v += __shfl_xor(v, 8);
        int slot = sb * ABLK + w * 32 + mt * 16 + l4 * 4 + r;
        if (l15 == 0 && slot < NPER) tot += v + b4v;
      }
    tot *= (1.f / NMODELS);
#pragma unroll
    for (int off = 1; off < 64; off <<= 1) tot += __shfl_xor(tot, off);
    if (l == 0) atomicAdd(out, tot);
  } // unit loop
}

extern "C" void kernel_launch(void* const* d_in, const int* in_sizes, int n_in,
                              void* d_out, int out_size, void* d_ws, size_t ws_size,
                              hipStream_t stream) {
  (void)in_sizes; (void)n_in; (void)out_size; (void)ws_size;
  const int* species = (const int*)d_in[0];
  const float* aev = (const float*)d_in[1];
  const float* W1 = (const float*)d_in[2];
  const float* b1 = (const float*)d_in[3];
  const float* W2 = (const float*)d_in[4];
  const float* b2 = (const float*)d_in[5];
  const float* W3 = (const float*)d_in[6];
  const float* b3 = (const float*)d_in[7];
  const float* W4 = (const float*)d_in[8];
  const float* b4 = (const float*)d_in[9];
  float* out = (float*)d_out;
  char* ws = (char*)d_ws;

  unsigned short* pAll = (unsigned short*)ws;
  unsigned short* pPar = (unsigned short*)(ws + PBIAS_OFF);
  int* order = (int*)(ws + ORDER_OFF);
  int* bcnt = (int*)(ws + BCNT_OFF);
  int* bpfx = (int*)(ws + BPFX_OFF);
  int* base = (int*)(ws + BASE_OFF);
  unsigned short* aevb = (unsigned short*)(ws + AEVB_OFF);
  int* uctr = (int*)(ws + CTR_OFF);

  hipMemsetAsync(d_out, 0, sizeof(float), stream);
  hipMemsetAsync(uctr, 0, sizeof(int), stream);

  count_kernel<<<NRBLK, 256, 0, stream>>>(species, bcnt);
  scan_kernel<<<1, 256, 0, stream>>>(bcnt, bpfx, base);
  route_kernel<<<NRBLK, 256, 0, stream>>>(species, bpfx, base, order);

  {
    int total = NSP * NPAD * (D0 / 8);  // 2,408,448 threads
    aev_pack<<<total / 256, 256, 0, stream>>>(aev, order, aevb);
  }
  {
    int total = NSP * NMODELS * D0 * D1 / 2;
    pack_kernel<<<(total + 255) / 256, 256, 0, stream>>>(W1, (unsigned*)pAll, D0, D1, D1 / 16, 0, total);
  }
  {
    int total = NSP * NMODELS * D1 * D2 / 2;
    pack_kernel<<<(total + 255) / 256, 256, 0, stream>>>(W2, (unsigned*)pAll, D1, D2, D2 / 16, 120, total);
  }
  {
    int total = NSP * NMODELS * D2 * D3 / 2;
    pack_kernel<<<(total + 255) / 256, 256, 0, stream>>>(W3, (unsigned*)pAll, D2, D3, D3 / 16, 160, total);
  }
  {
    int total = NSP * NMODELS * 512;
    param_pack<<<(total + 255) / 256, 256, 0, stream>>>(b1, b2, b3, W4, b4, pPar);
  }

  mlp_kernel<<<NWORK, 256, 0, stream>>>(aevb, pAll, pPar, uctr, out);
}

// Round 10
// 249.193 us; speedup vs baseline: 1.0898x; 1.0898x over previous
//
#include <hip/hip_runtime.h>

// BmmEnsemble: species-routed 4x8 MLP ensemble (384->160->128->96->1, CELU 0.1),
// mean over 8 models, global sum -> scalar.
// R15: SWAPPED OPERANDS, NO hbuf -> 3 blocks/CU + balanced grid.
// Every layer computes mfma(A=W-frag, B=atom/h-frag) so D = [n][atom].
// Layer->layer A-transpose (the reason hbuf existed) becomes a static
// 8-shfl-per-frag lane permutation of cvt_pk'd pairs:
//   target frag(mt,kf) elem e: src lane ((l4&1)*2+(e>=4))*16+l15,
//   src pair-reg pk[2kf+(l4>>1)][e>>2], half e&1 -- all compile-time.
// LDS = 16KB (weight stage only) -> 3 blocks/CU (launch_bounds(256,3));
// 784 blocks = 1.02 generations of 3/CU (near-perfect balance, static
// XCD-local). Atom frags stream from frag-ordered aevf with a 2-slot
// register window (compile-time kf schedule, 1-chunk prefetch slack).
// Chunk loop = R9's plain 2-buffer __syncthreads (counted vmcnt would be
// poisoned by the atom-window VGPR loads).

#define NSP 4
#define NMODELS 8
#define MSPLIT 2
#define MPB (NMODELS / MSPLIT)       // 4 models per block
#define NATOMS 50000
#define NPER (NATOMS / NSP)          // 12500
#define NPAD 12544                   // 98*128 padded rows per species
#define NG16 (NPAD / 16)             // 784 16-atom groups per species
#define D0 384
#define D1 160
#define D2 128
#define D3 96
#define NRBLK ((NATOMS + 255) / 256) // 196
#define ABLK 128
#define BPS ((NPER + ABLK - 1) / ABLK) // 98 blocks per species
#define FRAGS_SM 184                  // 120 (W1) + 40 (W2) + 24 (W3) fragments
#define CHUNKS_M 23                   // 184 frags / 8 per chunk
#define TOT_CHUNKS (MPB * CHUNKS_M)   // 92 chunks per block
#define MAXKF(c) ((8 * (c) + 7) / 10)

typedef float f32x4 __attribute__((ext_vector_type(4)));
typedef __bf16 bf16x8 __attribute__((ext_vector_type(8)));

#define MFMA16(a, b, c) __builtin_amdgcn_mfma_f32_16x16x32_bf16((a), (b), (c), 0, 0, 0)

// ---- workspace layout (bytes) ----
#define PALL_BYTES ((size_t)NSP * NMODELS * FRAGS_SM * 1024)
#define PBIAS_OFF PALL_BYTES
#define PBIAS_BYTES ((size_t)NSP * NMODELS * 512 * 2)   // 1KB per (s,m)
#define ORDER_OFF (PBIAS_OFF + PBIAS_BYTES)
#define BCNT_OFF (ORDER_OFF + (size_t)NATOMS * 4)
#define BPFX_OFF (BCNT_OFF + (size_t)NRBLK * NSP * 4)
#define BASE_OFF (BPFX_OFF + (size_t)NRBLK * NSP * 4)
#define AEVF_OFF (BASE_OFF + 1024)                      // 64B-aligned
#define AEVF_BYTES ((size_t)NSP * NG16 * 12 * 1024)     // 38.5 MB frag-ordered

static __device__ __forceinline__ unsigned short bfbits(float f) {
  __bf16 h = (__bf16)f;
  return __builtin_bit_cast(unsigned short, h);
}

static __device__ __forceinline__ float bf2f(unsigned short u) {
  return (float)__builtin_bit_cast(__bf16, u);
}

static __device__ __forceinline__ float celu01(float x) {
  // celu(x, alpha=0.1) = max(x,0) + min(0, 0.1*(exp(x/0.1)-1))
  return fmaxf(x, 0.f) + 0.1f * fminf(0.f, __expf(x * 10.f) - 1.f);
}

// async global->LDS, 16 B per lane; LDS dest = wave-uniform base + lane*16
static __device__ __forceinline__ void gload16(const void* g, void* l) {
  __builtin_amdgcn_global_load_lds(
      (const __attribute__((address_space(1))) unsigned int*)g,
      (__attribute__((address_space(3))) unsigned int*)l, 16, 0, 0);
}

// ---------------- routing ----------------
__global__ __launch_bounds__(256) void count_kernel(const int* __restrict__ species,
                                                    int* __restrict__ bcnt) {
  __shared__ int cnt[NSP];
  int t = threadIdx.x;
  if (t < NSP) cnt[t] = 0;
  __syncthreads();
  int i = blockIdx.x * 256 + t;
  if (i < NATOMS) atomicAdd(&cnt[species[i]], 1);
  __syncthreads();
  if (t < NSP) bcnt[blockIdx.x * NSP + t] = cnt[t];
}

__global__ __launch_bounds__(256) void scan_kernel(const int* __restrict__ bcnt,
                                                   int* __restrict__ bpfx,
                                                   int* __restrict__ base) {
  int w = threadIdx.x >> 6;
  int lane = threadIdx.x & 63;
  __shared__ int totals[NSP];
  int carry = 0;
  for (int c = 0; c < (NRBLK + 63) / 64; ++c) {
    int idx = c * 64 + lane;
    int v = (idx < NRBLK) ? bcnt[idx * NSP + w] : 0;
    int incl = v;
    for (int off = 1; off < 64; off <<= 1) {
      int tv = __shfl_up(incl, off);
      if (lane >= off) incl += tv;
    }
    if (idx < NRBLK) bpfx[idx * NSP + w] = carry + incl - v;
    carry += __shfl(incl, 63);
  }
  if (lane == 0) totals[w] = carry;
  __syncthreads();
  if (threadIdx.x == 0) {
    int run = 0;
    for (int s = 0; s < NSP; ++s) { base[s] = run; run += totals[s]; }
  }
}

__global__ __launch_bounds__(256) void route_kernel(const int* __restrict__ species,
                                                    const int* __restrict__ bpfx,
                                                    const int* __restrict__ base,
                                                    int* __restrict__ order) {
  __shared__ int sp[256];
  int t = threadIdx.x;
  int i = blockIdx.x * 256 + t;
  sp[t] = (i < NATOMS) ? species[i] : -1;
  __syncthreads();
  if (i < NATOMS) {
    int s = sp[t];
    int rank = 0;
    for (int j = 0; j < t; ++j) rank += (sp[j] == s) ? 1 : 0;
    order[base[s] + bpfx[blockIdx.x * NSP + s] + rank] = i;
  }
}

// ---------------- routed bf16 aev pre-pack, B-FRAGMENT ORDER ----------------
// frag index = (s*NG16 + g16)*12 + kf ; lane l elem e holds
// aev[atom = g16*16 + (l&15)][k = kf*32 + (l>>4)*8 + e] (pads -> 0).
__global__ __launch_bounds__(256) void aev_pack(const float* __restrict__ aev,
                                                const int* __restrict__ order,
                                                unsigned short* __restrict__ aevf) {
  int tid = blockIdx.x * 256 + threadIdx.x;   // NSP*NG16*12*64 total
  int frag = tid >> 6;
  int l = tid & 63;
  if (frag >= NSP * NG16 * 12) return;
  int s = frag / (NG16 * 12);
  int r2 = frag - s * (NG16 * 12);
  int g16 = r2 / 12;
  int kf = r2 - g16 * 12;
  int slot = g16 * 16 + (l & 15);
  int k0 = kf * 32 + (l >> 4) * 8;
  unsigned short o[8];
  if (slot < NPER) {
    int src = order[s * NPER + slot];
    const float4* q = (const float4*)(aev + (size_t)src * D0 + k0);
    float4 v0 = q[0], v1 = q[1];
    o[0] = bfbits(v0.x); o[1] = bfbits(v0.y); o[2] = bfbits(v0.z); o[3] = bfbits(v0.w);
    o[4] = bfbits(v1.x); o[5] = bfbits(v1.y); o[6] = bfbits(v1.z); o[7] = bfbits(v1.w);
  } else {
#pragma unroll
    for (int e = 0; e < 8; ++e) o[e] = 0;
  }
  *(int4*)(aevf + ((size_t)frag << 9) + l * 8) = *(const int4*)o;
}

// ---------------- weight pre-pack into contiguous fragment stream ----------------
// pAll: per (s,m) block of FRAGS_SM fragments (1 KB each). Frag order within a
// layer: f = kf*NT + nt. Lane l, elem e: k = kf*32 + 8*(l>>4) + e ; n = nt*16 + (l&15).
// (Same bytes serve as the A-operand in the swapped convention.)
__global__ __launch_bounds__(256) void pack_kernel(const float* __restrict__ W,
                                                   unsigned* __restrict__ dst,
                                                   int K, int N, int NT, int fragBase,
                                                   int total) {
  int tid = blockIdx.x * 256 + threadIdx.x;
  if (tid >= total) return;
  int per_sm = K * N / 2;            // dwords per (s,m)
  int smi = tid / per_sm;
  int rem = tid - smi * per_sm;
  int frag = rem >> 8;               // 256 dwords per fragment
  int wi = rem & 255;
  int l = wi >> 2, d = wi & 3;
  int kf = frag / NT;
  int nt = frag - kf * NT;
  int k = kf * 32 + ((l >> 4) << 3) + 2 * d;
  int n = nt * 16 + (l & 15);
  const float* p = W + ((size_t)smi * K + k) * N + n;
  unsigned lo = bfbits(p[0]);
  unsigned hi = bfbits(p[N]);
  dst[((size_t)smi * FRAGS_SM + fragBase + frag) * 256 + wi] = lo | (hi << 16);
}

// param pack: per (s,m) record of 512 shorts:
// [0:160) b1 bf16 | [160:288) b2 bf16 | [288:384) b3 bf16 | [384:480) W4 bf16 |
// [480:482) b4 as f32 bit halves | rest 0
__global__ __launch_bounds__(256) void param_pack(const float* __restrict__ b1,
                                                  const float* __restrict__ b2,
                                                  const float* __restrict__ b3,
                                                  const float* __restrict__ W4,
                                                  const float* __restrict__ b4,
                                                  unsigned short* __restrict__ dst) {
  int i = blockIdx.x * 256 + threadIdx.x;
  if (i >= NSP * NMODELS * 512) return;
  int smi = i >> 9, o = i & 511;
  unsigned short v = 0;
  if (o < 160) v = bfbits(b1[smi * 160 + o]);
  else if (o < 288) v = bfbits(b2[smi * 128 + (o - 160)]);
  else if (o < 384) v = bfbits(b3[smi * 96 + (o - 288)]);
  else if (o < 480) v = bfbits(W4[smi * 96 + (o - 384)]);
  else if (o < 482) {
    unsigned u = __builtin_bit_cast(unsigned, b4[smi]);
    v = (unsigned short)((o == 480) ? (u & 0xffffu) : (u >> 16));
  }
  dst[i] = v;
}

// ---------------- fused MLP (swapped operands, LDS = weight stage only) ----------------
__global__ __launch_bounds__(256, 3) void mlp_kernel(
    const unsigned short* __restrict__ aevf,
    const unsigned short* __restrict__ pAll, const unsigned short* __restrict__ pPar,
    float* __restrict__ out) {
  __shared__ alignas(16) unsigned short stage[2][4096]; // 16384 B total

  // XCD-aware swizzle (784 % 8 == 0)
  const int nwg = NSP * BPS * MSPLIT;
  const int cpx = nwg / 8;
  const int blk = (blockIdx.x % 8) * cpx + blockIdx.x / 8;
  const int s = blk / (BPS * MSPLIT);
  const int rem = blk - s * (BPS * MSPLIT);
  const int mh = rem / BPS;          // model half: models mh*4 .. mh*4+3
  const int sb = rem - mh * BPS;     // atom block within species
  const int tid = threadIdx.x;
  const int w = tid >> 6;
  const int l = tid & 63;
  const int l15 = l & 15;
  const int l4 = l >> 4;

  // per-wave weight-stream source (2KB of each 8KB chunk)
  const size_t smBase = (size_t)(s * NMODELS + mh * MPB) * FRAGS_SM;
  const char* wsrc = (const char*)pAll + smBase * 1024 + (size_t)w * 2048 + (size_t)l * 16;

  // atom fragment base: g16 = sb*8 + w*2 + mt
  const size_t afr = ((size_t)s * NG16 + sb * 8 + w * 2) * 12;
  auto ldB = [&](int mt, int kf) -> bf16x8 {
    return *(const bf16x8*)(aevf + ((afr + (size_t)mt * 12 + kf) << 9) + l * 8);
  };

  // shuffle-transpose constants (see header comment)
  const int src0 = ((l4 & 1) << 5) | l15;
  const int src1 = src0 + 16;
  const bool hiSel = (l4 & 2) != 0;

  // atom window: bw[mt][kf&1]
  bf16x8 bw[2][2];
  bw[0][0] = ldB(0, 0);
  bw[1][0] = ldB(1, 0);

  float accE[2] = {0.f, 0.f};
  float bbacc = 0.f;

  // stage chunk 0; first sync drains it
  {
    char* d = (char*)stage + w * 2048;
    gload16(wsrc, d);
    gload16(wsrc + 1024, d + 1024);
  }
  __syncthreads();

  auto stage_next = [&](int gn) {
    if (gn < TOT_CHUNKS) {
      char* d = (char*)stage + (gn & 1) * 8192 + w * 2048;
      const char* sp = wsrc + (size_t)gn * 8192;
      gload16(sp, d);
      gload16(sp + 1024, d + 1024);
    }
  };

  int gc = 0;

#pragma unroll 1
  for (int m = 0; m < MPB; ++m) {
    const unsigned short* pb = pPar + (size_t)(s * NMODELS + mh * MPB + m) * 512;

    // ===== Layer 1: D1[n][atom], 15 chunks; atom frags via 2-slot window =====
    f32x4 C1[2][10];
#pragma unroll
    for (int mt = 0; mt < 2; ++mt)
#pragma unroll
      for (int nt = 0; nt < 10; ++nt) {
        f32x4 z; z[0] = z[1] = z[2] = z[3] = 0.f; C1[mt][nt] = z;
      }
#pragma unroll
    for (int c = 0; c < 15; ++c) {
      stage_next(gc + 1);
      if (c < 14 && MAXKF(c + 1) > MAXKF(c)) {   // compile-time schedule
        const int nk = MAXKF(c + 1);
        bw[0][nk & 1] = ldB(0, nk);
        bw[1][nk & 1] = ldB(1, nk);
      }
      const bf16x8* sbuf = (const bf16x8*)((const char*)stage + (gc & 1) * 8192);
#pragma unroll
      for (int j = 0; j < 8; ++j) {
        const int f = c * 8 + j;    // kf = f/10, nt = f%10 (compile-time)
        bf16x8 wA = sbuf[j * 64 + l];
        C1[0][f % 10] = MFMA16(wA, bw[0][(f / 10) & 1], C1[0][f % 10]);
        C1[1][f % 10] = MFMA16(wA, bw[1][(f / 10) & 1], C1[1][f % 10]);
      }
      __syncthreads();
      ++gc;
    }

    // ---- L1 epilogue: bias+celu, pack pairs, shuffle-transpose -> b2 frags ----
    bf16x8 b2[2][5];
    {
      ushort4 bv[10];
#pragma unroll
      for (int nt = 0; nt < 10; ++nt)
        bv[nt] = *(const ushort4*)(pb + nt * 16 + (l4 << 2));
#pragma unroll
      for (int mt = 0; mt < 2; ++mt) {
        unsigned pk[10][2];
#pragma unroll
        for (int nt = 0; nt < 10; ++nt) {
          float h0 = celu01(C1[mt][nt][0] + bf2f(bv[nt].x));
          float h1 = celu01(C1[mt][nt][1] + bf2f(bv[nt].y));
          float h2 = celu01(C1[mt][nt][2] + bf2f(bv[nt].z));
          float h3 = celu01(C1[mt][nt][3] + bf2f(bv[nt].w));
          pk[nt][0] = (unsigned)bfbits(h0) | ((unsigned)bfbits(h1) << 16);
          pk[nt][1] = (unsigned)bfbits(h2) | ((unsigned)bfbits(h3) << 16);
        }
#pragma unroll
        for (int kf = 0; kf < 5; ++kf) {
          int d0a = __shfl((int)pk[2 * kf][0], src0), d0b = __shfl((int)pk[2 * kf + 1][0], src0);
          int d1a = __shfl((int)pk[2 * kf][1], src0), d1b = __shfl((int)pk[2 * kf + 1][1], src0);
          int d2a = __shfl((int)pk[2 * kf][0], src1), d2b = __shfl((int)pk[2 * kf + 1][0], src1);
          int d3a = __shfl((int)pk[2 * kf][1], src1), d3b = __shfl((int)pk[2 * kf + 1][1], src1);
          int4 di;
          di.x = hiSel ? d0b : d0a;
          di.y = hiSel ? d1b : d1a;
          di.z = hiSel ? d2b : d2a;
          di.w = hiSel ? d3b : d3a;
          b2[mt][kf] = __builtin_bit_cast(bf16x8, di);
        }
      }
    }

    // ===== Layer 2: 5 chunks (kf2 = c2, nt2 = j) =====
    f32x4 C2[2][8];
#pragma unroll
    for (int mt = 0; mt < 2; ++mt)
#pragma unroll
      for (int nt = 0; nt < 8; ++nt) {
        f32x4 z; z[0] = z[1] = z[2] = z[3] = 0.f; C2[mt][nt] = z;
      }
#pragma unroll
    for (int c2 = 0; c2 < 5; ++c2) {
      stage_next(gc + 1);
      const bf16x8* sbuf = (const bf16x8*)((const char*)stage + (gc & 1) * 8192);
#pragma unroll
      for (int j = 0; j < 8; ++j) {
        bf16x8 wA = sbuf[j * 64 + l];
        C2[0][j] = MFMA16(wA, b2[0][c2], C2[0][j]);
        C2[1][j] = MFMA16(wA, b2[1][c2], C2[1][j]);
      }
      __syncthreads();
      ++gc;
    }

    // ---- L2 epilogue -> b3 frags (same transform, NTT=8) ----
    bf16x8 b3[2][4];
    {
      ushort4 bv[8];
#pragma unroll
      for (int nt = 0; nt < 8; ++nt)
        bv[nt] = *(const ushort4*)(pb + 160 + nt * 16 + (l4 << 2));
#pragma unroll
      for (int mt = 0; mt < 2; ++mt) {
        unsigned pk[8][2];
#pragma unroll
        for (int nt = 0; nt < 8; ++nt) {
          float h0 = celu01(C2[mt][nt][0] + bf2f(bv[nt].x));
          float h1 = celu01(C2[mt][nt][1] + bf2f(bv[nt].y));
          float h2 = celu01(C2[mt][nt][2] + bf2f(bv[nt].z));
          float h3 = celu01(C2[mt][nt][3] + bf2f(bv[nt].w));
          pk[nt][0] = (unsigned)bfbits(h0) | ((unsigned)bfbits(h1) << 16);
          pk[nt][1] = (unsigned)bfbits(h2) | ((unsigned)bfbits(h3) << 16);
        }
#pragma unroll
        for (int kf = 0; kf < 4; ++kf) {
          int d0a = __shfl((int)pk[2 * kf][0], src0), d0b = __shfl((int)pk[2 * kf + 1][0], src0);
          int d1a = __shfl((int)pk[2 * kf][1], src0), d1b = __shfl((int)pk[2 * kf + 1][1], src0);
          int d2a = __shfl((int)pk[2 * kf][0], src1), d2b = __shfl((int)pk[2 * kf + 1][0], src1);
          int d3a = __shfl((int)pk[2 * kf][1], src1), d3b = __shfl((int)pk[2 * kf + 1][1], src1);
          int4 di;
          di.x = hiSel ? d0b : d0a;
          di.y = hiSel ? d1b : d1a;
          di.z = hiSel ? d2b : d2a;
          di.w = hiSel ? d3b : d3a;
          b3[mt][kf] = __builtin_bit_cast(bf16x8, di);
        }
      }
    }

    // ===== Layer 3: 3 chunks (kf3 = f/6, nt3 = f%6); reload atom kf0 window =====
    f32x4 C3[2][6];
#pragma unroll
    for (int mt = 0; mt < 2; ++mt)
#pragma unroll
      for (int nt = 0; nt < 6; ++nt) {
        f32x4 z; z[0] = z[1] = z[2] = z[3] = 0.f; C3[mt][nt] = z;
      }
#pragma unroll
    for (int lc = 0; lc < 3; ++lc) {
      stage_next(gc + 1);
      if (lc == 0) {  // prefetch next model's first atom frags (model-indep.)
        bw[0][0] = ldB(0, 0);
        bw[1][0] = ldB(1, 0);
      }
      const bf16x8* sbuf = (const bf16x8*)((const char*)stage + (gc & 1) * 8192);
#pragma unroll
      for (int j = 0; j < 8; ++j) {
        const int f = lc * 8 + j;
        bf16x8 wA = sbuf[j * 64 + l];
        C3[0][f % 6] = MFMA16(wA, b3[0][f / 6], C3[0][f % 6]);
        C3[1][f % 6] = MFMA16(wA, b3[1][f / 6], C3[1][f % 6]);
      }
      __syncthreads();
      ++gc;
    }

    // ===== Layer 4: per-lane fold over this lane's n3 slice =====
#pragma unroll
    for (int nt = 0; nt < 6; ++nt) {
      ushort4 b3v = *(const ushort4*)(pb + 288 + nt * 16 + (l4 << 2));
      ushort4 w4v = *(const ushort4*)(pb + 384 + nt * 16 + (l4 << 2));
      float bb[4] = {bf2f(b3v.x), bf2f(b3v.y), bf2f(b3v.z), bf2f(b3v.w)};
      float ww[4] = {bf2f(w4v.x), bf2f(w4v.y), bf2f(w4v.z), bf2f(w4v.w)};
#pragma unroll
      for (int mt = 0; mt < 2; ++mt)
#pragma unroll
        for (int r = 0; r < 4; ++r)
          accE[mt] += celu01(C3[mt][nt][r] + bb[r]) * ww[r];
    }
    bbacc += ((const float*)pPar)[(size_t)(s * NMODELS + mh * MPB + m) * 256 + 240];
  } // models

  // ---- final: reduce over l4 groups (n-slices), mask pads, sum, atomic ----
  float tot = 0.f;
#pragma unroll
  for (int mt = 0; mt < 2; ++mt) {
    float v = accE[mt];
    v += __shfl_xor(v, 16);
    v += __shfl_xor(v, 32);
    int slot = sb * ABLK + w * 32 + mt * 16 + l15;
    if (l < 16 && slot < NPER) tot += v + bbacc;
  }
  tot *= (1.f / NMODELS);
#pragma unroll
  for (int off = 1; off < 64; off <<= 1) tot += __shfl_xor(tot, off);
  if (l == 0) atomicAdd(out, tot);
}

extern "C" void kernel_launch(void* const* d_in, const int* in_sizes, int n_in,
                              void* d_out, int out_size, void* d_ws, size_t ws_size,
                              hipStream_t stream) {
  (void)in_sizes; (void)n_in; (void)out_size; (void)ws_size;
  const int* species = (const int*)d_in[0];
  const float* aev = (const float*)d_in[1];
  const float* W1 = (const float*)d_in[2];
  const float* b1 = (const float*)d_in[3];
  const float* W2 = (const float*)d_in[4];
  const float* b2 = (const float*)d_in[5];
  const float* W3 = (const float*)d_in[6];
  const float* b3 = (const float*)d_in[7];
  const float* W4 = (const float*)d_in[8];
  const float* b4 = (const float*)d_in[9];
  float* out = (float*)d_out;
  char* ws = (char*)d_ws;

  unsigned short* pAll = (unsigned short*)ws;
  unsigned short* pPar = (unsigned short*)(ws + PBIAS_OFF);
  int* order = (int*)(ws + ORDER_OFF);
  int* bcnt = (int*)(ws + BCNT_OFF);
  int* bpfx = (int*)(ws + BPFX_OFF);
  int* base = (int*)(ws + BASE_OFF);
  unsigned short* aevf = (unsigned short*)(ws + AEVF_OFF);

  hipMemsetAsync(d_out, 0, sizeof(float), stream);

  count_kernel<<<NRBLK, 256, 0, stream>>>(species, bcnt);
  scan_kernel<<<1, 256, 0, stream>>>(bcnt, bpfx, base);
  route_kernel<<<NRBLK, 256, 0, stream>>>(species, bpfx, base, order);

  {
    int total = NSP * NG16 * 12 * 64;   // 2,408,448 threads
    aev_pack<<<(total + 255) / 256, 256, 0, stream>>>(aev, order, aevf);
  }
  {
    int total = NSP * NMODELS * D0 * D1 / 2;
    pack_kernel<<<(total + 255) / 256, 256, 0, stream>>>(W1, (unsigned*)pAll, D0, D1, D1 / 16, 0, total);
  }
  {
    int total = NSP * NMODELS * D1 * D2 / 2;
    pack_kernel<<<(total + 255) / 256, 256, 0, stream>>>(W2, (unsigned*)pAll, D1, D2, D2 / 16, 120, total);
  }
  {
    int total = NSP * NMODELS * D2 * D3 / 2;
    pack_kernel<<<(total + 255) / 256, 256, 0, stream>>>(W3, (unsigned*)pAll, D2, D3, D3 / 16, 160, total);
  }
  {
    int total = NSP * NMODELS * 512;
    param_pack<<<(total + 255) / 256, 256, 0, stream>>>(b1, b2, b3, W4, b4, pPar);
  }

  mlp_kernel<<<NSP * BPS * MSPLIT, 256, 0, stream>>>(aevf, pAll, pPar, out);
}